// Round 2
// baseline (486.413 us; speedup 1.0000x reference)
//
#include <hip/hip_runtime.h>

// ============================================================================
// ExtraMHSA fused pipeline for MI355X (gfx950).  R2: occupancy-focused.
//
//   prep_all   : BN-fold weights->bf16, x transpose->bf16, pos embeds (fused)
//   gemm_x1    : x1T = silu(conv1(x))             [6400][128] bf16
//   gemm_qkvp  : q,k,v,p -> LT/RT/V/pT layouts
//   attn_kernel: 64-row i-tiles (4 waves x 16 rows), jp=4 -> 800 blocks,
//                3 blocks/CU by LDS (42KB). S=exp(L^T R) no-max softmax
//                (scores bounded ~26), O += P*V^T, partial O/l per jp.
//   final_k    : folds partial-sum + 1/l + conv2/conv3 BN silu + residual.
// ============================================================================

typedef unsigned short u16;
typedef __attribute__((ext_vector_type(8))) short bf16x8;   // 8 bf16 = 4 VGPRs
typedef __attribute__((ext_vector_type(4))) float f32x4;    // MFMA C/D frag
typedef __attribute__((ext_vector_type(4))) unsigned int u32x4;

#define HW 6400
#define BN_EPS 1e-5f

__device__ __forceinline__ u16 f2b(float f) {       // fp32 -> bf16 RNE
  unsigned u = __float_as_uint(f);
  u += 0x7fffu + ((u >> 16) & 1u);
  return (u16)(u >> 16);
}
__device__ __forceinline__ unsigned pack2(float a, float b) {
  return (unsigned)f2b(a) | ((unsigned)f2b(b) << 16);
}
__device__ __forceinline__ f32x4 MFMA(bf16x8 a, bf16x8 b, f32x4 c) {
  return __builtin_amdgcn_mfma_f32_16x16x32_bf16(a, b, c, 0, 0, 0);
}
__device__ __forceinline__ float silu_f(float y) {
  return y / (1.0f + __expf(-y));
}
__device__ __forceinline__ bf16x8 pack8(f32x4 lo, f32x4 hi, float sc) {
  union { bf16x8 v; uint4 u; } r;
  r.u.x = pack2(lo[0] * sc, lo[1] * sc);
  r.u.y = pack2(lo[2] * sc, lo[3] * sc);
  r.u.z = pack2(hi[0] * sc, hi[1] * sc);
  r.u.w = pack2(hi[2] * sc, hi[3] * sc);
  return r.v;
}

// ---------------------------------------------------------------------------
// prep_all: blocks [0,800): xT transpose tiles; [800,880): pos embeds;
//           [880,944): weight BN-fold. One launch replaces three.
// ---------------------------------------------------------------------------
__global__ void prep_all(
    const float* __restrict__ x,
    const float* __restrict__ rel_h, const float* __restrict__ rel_w,
    const float* __restrict__ ef_h, const float* __restrict__ ef_w,
    const float* __restrict__ w1, const float* __restrict__ g1, const float* __restrict__ b1,
    const float* __restrict__ m1, const float* __restrict__ v1,
    const float* __restrict__ w2, const float* __restrict__ g2, const float* __restrict__ b2,
    const float* __restrict__ m2, const float* __restrict__ v2,
    const float* __restrict__ w3, const float* __restrict__ g3, const float* __restrict__ b3,
    const float* __restrict__ m3, const float* __restrict__ v3,
    const float* __restrict__ wq, const float* __restrict__ bq,
    const float* __restrict__ wk, const float* __restrict__ bk,
    const float* __restrict__ wv, const float* __restrict__ bv,
    const float* __restrict__ wp, const float* __restrict__ bp,
    u16* __restrict__ xT,
    u16* __restrict__ LT, u16* __restrict__ efT, u16* __restrict__ efc,
    u16* __restrict__ w1b, float* __restrict__ b1e,
    u16* __restrict__ Wcat, float* __restrict__ bcat,
    u16* __restrict__ w2b, float* __restrict__ b2e,
    u16* __restrict__ w3b, float* __restrict__ b3e)
{
  __shared__ float tile[32][65];
  const int b = blockIdx.x;
  const int t = threadIdx.x;
  if (b < 800) {
    // ---- x [256][6400] fp32 -> xT [6400][256] bf16, tile [32 d][64 i]
    const int d0 = (b & 7) * 32;
    const int i0 = (b >> 3) * 64;
    {
      const int dr = t >> 3;
      const int ic = (t & 7) * 8;
      const float* src = x + (size_t)(d0 + dr) * HW + i0 + ic;
      f32x4 a = *(const f32x4*)src;
      f32x4 bb = *(const f32x4*)(src + 4);
#pragma unroll
      for (int e = 0; e < 4; ++e) { tile[dr][ic + e] = a[e]; tile[dr][ic + 4 + e] = bb[e]; }
    }
    __syncthreads();
    {
      const int ir = t >> 2;
      const int dc = (t & 3) * 8;
      uint4 u;
      u.x = pack2(tile[dc + 0][ir], tile[dc + 1][ir]);
      u.y = pack2(tile[dc + 2][ir], tile[dc + 3][ir]);
      u.z = pack2(tile[dc + 4][ir], tile[dc + 5][ir]);
      u.w = pack2(tile[dc + 6][ir], tile[dc + 7][ir]);
      *(uint4*)(xT + (size_t)(i0 + ir) * 256 + d0 + dc) = u;
    }
  } else if (b < 880) {
    // ---- pos embeds, one block per h row
    const int h = b - 800;
    const int c0 = (t & 63) * 2;
    const float rh0 = rel_h[c0 * 80 + h], rh1 = rel_h[(c0 + 1) * 80 + h];
    const float eh0 = ef_h[c0 * 80 + h], eh1 = ef_h[(c0 + 1) * 80 + h];
    for (int wcol = (t >> 6); wcol < 80; wcol += 4) {
      const int i = h * 80 + wcol;
      float rw0 = rel_w[c0 * 80 + wcol], rw1 = rel_w[(c0 + 1) * 80 + wcol];
      float ew0 = ef_w[c0 * 80 + wcol], ew1 = ef_w[(c0 + 1) * 80 + wcol];
      *(unsigned*)&LT[(size_t)i * 256 + 128 + c0] = pack2(rh0 + rw0, rh1 + rw1);
      float e0 = eh0 + ew0, e1 = eh1 + ew1;
      *(unsigned*)&efT[(size_t)i * 128 + c0] = pack2(e0, e1);
      efc[(size_t)c0 * HW + i] = f2b(e0);
      efc[(size_t)(c0 + 1) * HW + i] = f2b(e1);
    }
  } else {
    // ---- weight BN-fold (stride loops over 64 blocks' worth of threads)
    const int tid = (b - 880) * 256 + t;
    const int stride = 64 * 256;
    for (int idx = tid; idx < 128 * 256; idx += stride) {
      int o = idx >> 8;
      float s = g1[o] * rsqrtf(v1[o] + BN_EPS);
      w1b[idx] = f2b(w1[idx] * s);
    }
    for (int idx = tid; idx < 128; idx += stride) {
      float s = g1[idx] * rsqrtf(v1[idx] + BN_EPS);
      b1e[idx] = b1[idx] - m1[idx] * s;
    }
    for (int idx = tid; idx < 4 * 128 * 128; idx += stride) {
      int which = idx >> 14, r = idx & 16383;
      const float* src = which == 0 ? wq : which == 1 ? wk : which == 2 ? wv : wp;
      Wcat[idx] = f2b(src[r]);
    }
    for (int idx = tid; idx < 512; idx += stride) {
      int which = idx >> 7, r = idx & 127;
      const float* src = which == 0 ? bq : which == 1 ? bk : which == 2 ? bv : bp;
      bcat[idx] = src[r];
    }
    for (int idx = tid; idx < 256 * 128; idx += stride) {
      int o = idx >> 7;
      float s2 = g2[o] * rsqrtf(v2[o] + BN_EPS);
      w2b[idx] = f2b(w2[idx] * s2);
      float s3 = g3[o] * rsqrtf(v3[o] + BN_EPS);
      w3b[idx] = f2b(w3[idx] * s3);
    }
    for (int idx = tid; idx < 256; idx += stride) {
      float s2 = g2[idx] * rsqrtf(v2[idx] + BN_EPS);
      b2e[idx] = b2[idx] - m2[idx] * s2;
      float s3 = g3[idx] * rsqrtf(v3[idx] + BN_EPS);
      b3e[idx] = b3[idx] - m3[idx] * s3;
    }
  }
}

// ---------------------------------------------------------------------------
// gemm_x1: x1T[i][c] = silu(xT[i][:] . w1b[c][:] + b1e[c]).  K=256, N=128.
// grid <<<200, 128>>>; 2 waves x 16 rows.
// ---------------------------------------------------------------------------
__global__ __launch_bounds__(128) void gemm_x1(
    const u16* __restrict__ xT, const u16* __restrict__ w1b,
    const float* __restrict__ b1e, u16* __restrict__ x1T)
{
  __shared__ __align__(16) u16 tr[2][16][136];
  const int t = threadIdx.x, w = t >> 6, lane = t & 63, jl = lane & 15, q = lane >> 4;
  const int i0 = blockIdx.x * 32 + w * 16;
  f32x4 acc[8];
#pragma unroll
  for (int nf = 0; nf < 8; ++nf) acc[nf] = (f32x4){0.f, 0.f, 0.f, 0.f};
#pragma unroll
  for (int ks = 0; ks < 8; ++ks) {
    bf16x8 a = *(const bf16x8*)(xT + (size_t)(i0 + jl) * 256 + ks * 32 + q * 8);
#pragma unroll
    for (int nf = 0; nf < 8; ++nf) {
      bf16x8 b = *(const bf16x8*)(w1b + (size_t)(nf * 16 + jl) * 256 + ks * 32 + q * 8);
      acc[nf] = MFMA(a, b, acc[nf]);
    }
  }
#pragma unroll
  for (int nf = 0; nf < 8; ++nf) {
    const int c = nf * 16 + jl;
    const float bias = b1e[c];
#pragma unroll
    for (int r = 0; r < 4; ++r)
      tr[w][q * 4 + r][c] = f2b(silu_f(acc[nf][r] + bias));
  }
  __syncthreads();
#pragma unroll
  for (int r = 0; r < 16; ++r) {
    unsigned val = *(const unsigned*)&tr[w][r][lane * 2];
    *(unsigned*)(x1T + (size_t)(i0 + r) * 128 + lane * 2) = val;
  }
}

// ---------------------------------------------------------------------------
// gemm_qkvp: [q|k|v|p] = x1T . Wcat^T + bcat, routed into attention layouts.
// grid dim3(200, 4), 128 thr.
// ---------------------------------------------------------------------------
__global__ __launch_bounds__(128) void gemm_qkvp(
    const u16* __restrict__ x1T, const u16* __restrict__ Wcat, const float* __restrict__ bcat,
    u16* __restrict__ LT, u16* __restrict__ RT, u16* __restrict__ Vv, u16* __restrict__ pT)
{
  __shared__ __align__(16) u16 tr[2][16][136];
  const int t = threadIdx.x, w = t >> 6, lane = t & 63, jl = lane & 15, q = lane >> 4;
  const int i0 = blockIdx.x * 32 + w * 16;
  const int nc = blockIdx.y;
  f32x4 acc[8];
#pragma unroll
  for (int nf = 0; nf < 8; ++nf) acc[nf] = (f32x4){0.f, 0.f, 0.f, 0.f};
#pragma unroll
  for (int ks = 0; ks < 4; ++ks) {
    bf16x8 a = *(const bf16x8*)(x1T + (size_t)(i0 + jl) * 128 + ks * 32 + q * 8);
#pragma unroll
    for (int nf = 0; nf < 8; ++nf) {
      bf16x8 b = *(const bf16x8*)(Wcat + (size_t)(nc * 128 + nf * 16 + jl) * 128 + ks * 32 + q * 8);
      acc[nf] = MFMA(a, b, acc[nf]);
    }
  }
  if (nc == 2) {                                 // V: [c][i] c-major, direct
#pragma unroll
    for (int nf = 0; nf < 8; ++nf) {
      const int c = nf * 16 + jl;
      const float bias = bcat[256 + c];
      uint2 pk;
      pk.x = pack2(acc[nf][0] + bias, acc[nf][1] + bias);
      pk.y = pack2(acc[nf][2] + bias, acc[nf][3] + bias);
      *(uint2*)(Vv + (size_t)c * HW + i0 + q * 4) = pk;
    }
  } else {
#pragma unroll
    for (int nf = 0; nf < 8; ++nf) {
      const int c = nf * 16 + jl;
      const float bias = bcat[nc * 128 + c];
#pragma unroll
      for (int r = 0; r < 4; ++r)
        tr[w][q * 4 + r][c] = f2b(acc[nf][r] + bias);
    }
    __syncthreads();
#pragma unroll
    for (int r = 0; r < 16; ++r) {
      unsigned val = *(const unsigned*)&tr[w][r][lane * 2];
      const size_t row = (size_t)(i0 + r);
      if (nc == 0) {
        *(unsigned*)(LT + row * 256 + lane * 2) = val;
        *(unsigned*)(RT + row * 256 + 128 + lane * 2) = val;
      } else if (nc == 1) {
        *(unsigned*)(RT + row * 256 + lane * 2) = val;
      } else {
        *(unsigned*)(pT + row * 128 + lane * 2) = val;
      }
    }
  }
}

// ---------------------------------------------------------------------------
// Attention. Block = 64 i-rows x one j-quarter; 4 waves x 16 rows.
// LDS = 32K (Rs, XOR-8 chunk swizzle) + 9K (Ps, pad 72) = 42 KB -> 3 blk/CU.
// ---------------------------------------------------------------------------
template <int KD>
__device__ __forceinline__ void attn_body(
    const u16* __restrict__ Lt,   // [HW][KD]  i-major (A-side)
    const u16* __restrict__ Rt,   // [HW][KD]  j-major (B-side)
    const u16* __restrict__ Vm,   // [128][HW] c-major (B-side of PV)
    float* __restrict__ Opart,    // [4][HW][128]
    float* __restrict__ lpart,    // [4][HW]
    int it, int jp, u16* Rs, u16* Ps)
{
  const int t = threadIdx.x;
  const int w = t >> 6, lane = t & 63, jl = lane & 15, q = lane >> 4;
  const int i0 = it * 64 + w * 16;
  constexpr int NKS = KD / 32;

  // A (L) fragments resident across the whole j-loop.
  bf16x8 afr[NKS];
#pragma unroll
  for (int ks = 0; ks < NKS; ++ks)
    afr[ks] = *(const bf16x8*)(Lt + (size_t)(i0 + jl) * KD + ks * 32 + q * 8);

  f32x4 o[8];
#pragma unroll
  for (int cf = 0; cf < 8; ++cf) o[cf] = (f32x4){0.f, 0.f, 0.f, 0.f};
  float ls[4] = {0.f, 0.f, 0.f, 0.f};

  u16* Psw = Ps + w * (16 * 72);
  const int jbase = jp * 1600;

  for (int stp = 0; stp < 25; ++stp) {
    const int jj = jbase + stp * 64;
    __syncthreads();                              // prev iter readers done
    // ---- stage R tile [64 j][KD] (XOR-8 16B-chunk swizzle)
    if constexpr (KD == 256) {
#pragma unroll
      for (int cc = 0; cc < 8; ++cc) {
        int jr = w * 16 + cc * 2 + (lane >> 5);
        int cp = lane & 31;
        int ch = (cp & ~7) | ((cp ^ jr) & 7);
        u32x4 val = *(const u32x4*)(Rt + (size_t)(jj + jr) * KD + ch * 8);
        *(u32x4*)(Rs + jr * 256 + cp * 8) = val;
      }
    } else {
#pragma unroll
      for (int cc = 0; cc < 4; ++cc) {
        int jr = w * 16 + cc * 4 + (lane >> 4);
        int cp = lane & 15;
        int ch = (cp & ~7) | ((cp ^ jr) & 7);
        u32x4 val = *(const u32x4*)(Rt + (size_t)(jj + jr) * KD + ch * 8);
        *(u32x4*)(Rs + jr * 128 + cp * 8) = val;
      }
    }
    __syncthreads();

    // ---- S tile: [16 i][64 j] per wave
    f32x4 s[4];
#pragma unroll
    for (int nf = 0; nf < 4; ++nf) s[nf] = (f32x4){0.f, 0.f, 0.f, 0.f};
#pragma unroll
    for (int nf = 0; nf < 4; ++nf) {
      const int row = nf * 16 + jl;
#pragma unroll
      for (int ks = 0; ks < NKS; ++ks) {
        const int ch = (ks * 4 + q) ^ (jl & 7);   // un-swizzle
        bf16x8 b = *(const bf16x8*)(Rs + row * KD + ch * 8);
        s[nf] = MFMA(afr[ks], b, s[nf]);
      }
    }
    // ---- P = exp(S); row sums; stage P in per-wave LDS (A-layout source)
    {
      float rsum[4] = {0.f, 0.f, 0.f, 0.f};
#pragma unroll
      for (int nf = 0; nf < 4; ++nf)
#pragma unroll
        for (int r = 0; r < 4; ++r) {
          float p = __expf(s[nf][r]);
          s[nf][r] = p;
          rsum[r] += p;
        }
#pragma unroll
      for (int d = 1; d < 16; d <<= 1)
#pragma unroll
        for (int r = 0; r < 4; ++r) rsum[r] += __shfl_xor(rsum[r], d);
#pragma unroll
      for (int r = 0; r < 4; ++r) ls[r] += rsum[r];
#pragma unroll
      for (int nf = 0; nf < 4; ++nf)
#pragma unroll
        for (int r = 0; r < 4; ++r)
          Psw[(q * 4 + r) * 72 + nf * 16 + jl] = f2b(s[nf][r]);
    }
    // ---- O += P . V^T  (V B-frags direct from global, L2-resident)
#pragma unroll
    for (int ks2 = 0; ks2 < 2; ++ks2) {
      bf16x8 a0 = *(const bf16x8*)(Psw + (size_t)jl * 72 + ks2 * 32 + q * 8);
#pragma unroll
      for (int cf = 0; cf < 8; ++cf) {
        bf16x8 b = *(const bf16x8*)(Vm + (size_t)(cf * 16 + jl) * HW + jj + ks2 * 32 + q * 8);
        o[cf] = MFMA(a0, b, o[cf]);
      }
    }
  }
  // ---- epilogue: plain stores to this jp's partial buffer
  float* Ob = Opart + (size_t)jp * HW * 128;
  const int ib = i0 + q * 4;
#pragma unroll
  for (int cf = 0; cf < 8; ++cf) {
    const int c = cf * 16 + jl;
#pragma unroll
    for (int r = 0; r < 4; ++r)
      Ob[(size_t)(ib + r) * 128 + c] = o[cf][r];
  }
  if (jl == 0) {
#pragma unroll
    for (int r = 0; r < 4; ++r)
      lpart[(size_t)jp * HW + ib + r] = ls[r];
  }
}

__global__ __launch_bounds__(256, 3) void attn_kernel(
    const u16* __restrict__ LT, const u16* __restrict__ RT, const u16* __restrict__ Vv,
    const u16* __restrict__ pT, const u16* __restrict__ efT, const u16* __restrict__ efc,
    float* __restrict__ Opart, float* __restrict__ lpart)
{
  __shared__ __align__(16) u16 Rs[64 * 256];      // 32 KB (head2 uses half)
  __shared__ __align__(16) u16 Ps[4 * 16 * 72];   // 9 KB  -> total 42 KB
  int b = blockIdx.x;
  if (b < 400) {
    attn_body<256>(LT, RT, Vv, Opart, lpart, b >> 2, b & 3, Rs, Ps);
  } else {
    b -= 400;
    attn_body<128>(pT, efT, efc, Opart + (size_t)4 * HW * 128, lpart + (size_t)4 * HW,
                   b >> 2, b & 3, Rs, Ps);
  }
}

// ---------------------------------------------------------------------------
// final_k: out[d][i] = x[d][i] + silu(o1.w2b + b2e) + silu(o2.w3b + b3e)
// where o?[i][c] = (sum_p Opart[p][i][c]) / (sum_p lpart[p][i]), built as
// bf16 A-fragments on the fly. grid dim3(100, 2), 256 thr.
// ---------------------------------------------------------------------------
__global__ __launch_bounds__(256) void final_k(
    const float* __restrict__ Opart,   // [2][4][HW][128]
    const float* __restrict__ lpart,   // [2][4][HW]
    const u16* __restrict__ w2b, const float* __restrict__ b2e,
    const u16* __restrict__ w3b, const float* __restrict__ b3e,
    const float* __restrict__ x, float* __restrict__ outp)
{
  const int t = threadIdx.x, w = t >> 6, lane = t & 63, jl = lane & 15, q = lane >> 4;
  const int i0 = blockIdx.x * 64 + w * 16;
  const int nc = blockIdx.y;
  const int row = i0 + jl;

  float l1 = 0.f, l2 = 0.f;
#pragma unroll
  for (int p = 0; p < 4; ++p) {
    l1 += lpart[(size_t)p * HW + row];
    l2 += lpart[(size_t)(4 + p) * HW + row];
  }
  const float inv1 = 1.0f / l1, inv2 = 1.0f / l2;
  const float* O1 = Opart;
  const float* O2 = Opart + (size_t)4 * HW * 128;

  f32x4 a1[8], a2[8];
#pragma unroll
  for (int nf = 0; nf < 8; ++nf) {
    a1[nf] = (f32x4){0.f, 0.f, 0.f, 0.f};
    a2[nf] = (f32x4){0.f, 0.f, 0.f, 0.f};
  }
#pragma unroll
  for (int ks = 0; ks < 4; ++ks) {
    f32x4 s1a = {0.f,0.f,0.f,0.f}, s1b = {0.f,0.f,0.f,0.f};
    f32x4 s2a = {0.f,0.f,0.f,0.f}, s2b = {0.f,0.f,0.f,0.f};
#pragma unroll
    for (int p = 0; p < 4; ++p) {
      const float* base1 = O1 + ((size_t)p * HW + row) * 128 + ks * 32 + q * 8;
      s1a += *(const f32x4*)base1;
      s1b += *(const f32x4*)(base1 + 4);
      const float* base2 = O2 + ((size_t)p * HW + row) * 128 + ks * 32 + q * 8;
      s2a += *(const f32x4*)base2;
      s2b += *(const f32x4*)(base2 + 4);
    }
    bf16x8 fa1 = pack8(s1a, s1b, inv1);
    bf16x8 fa2 = pack8(s2a, s2b, inv2);
#pragma unroll
    for (int nf = 0; nf < 8; ++nf) {
      bf16x8 b2f = *(const bf16x8*)(w2b + (size_t)(nc * 128 + nf * 16 + jl) * 128 + ks * 32 + q * 8);
      bf16x8 b3f = *(const bf16x8*)(w3b + (size_t)(nc * 128 + nf * 16 + jl) * 128 + ks * 32 + q * 8);
      a1[nf] = MFMA(fa1, b2f, a1[nf]);
      a2[nf] = MFMA(fa2, b3f, a2[nf]);
    }
  }
#pragma unroll
  for (int nf = 0; nf < 8; ++nf) {
    const int d = nc * 128 + nf * 16 + jl;
    const float bb2 = b2e[d], bb3 = b3e[d];
    const size_t base = (size_t)d * HW + i0 + q * 4;
    f32x4 xv = *(const f32x4*)(x + base);
    f32x4 rv;
#pragma unroll
    for (int r = 0; r < 4; ++r)
      rv[r] = xv[r] + silu_f(a1[nf][r] + bb2) + silu_f(a2[nf][r] + bb3);
    *(f32x4*)(outp + base) = rv;
  }
}

// ---------------------------------------------------------------------------
extern "C" void kernel_launch(void* const* d_in, const int* in_sizes, int n_in,
                              void* d_out, int out_size, void* d_ws, size_t ws_size,
                              hipStream_t stream)
{
  (void)in_sizes; (void)n_in; (void)out_size; (void)ws_size;
  const float* x   = (const float*)d_in[0];
  const float* w1  = (const float*)d_in[1];
  const float* g1  = (const float*)d_in[2];
  const float* b1  = (const float*)d_in[3];
  const float* m1  = (const float*)d_in[4];
  const float* v1  = (const float*)d_in[5];
  const float* w2  = (const float*)d_in[6];
  const float* g2  = (const float*)d_in[7];
  const float* b2  = (const float*)d_in[8];
  const float* m2  = (const float*)d_in[9];
  const float* v2  = (const float*)d_in[10];
  const float* w3  = (const float*)d_in[11];
  const float* g3  = (const float*)d_in[12];
  const float* b3  = (const float*)d_in[13];
  const float* m3  = (const float*)d_in[14];
  const float* v3  = (const float*)d_in[15];
  const float* wq  = (const float*)d_in[16];
  const float* bq  = (const float*)d_in[17];
  const float* wk  = (const float*)d_in[18];
  const float* bk  = (const float*)d_in[19];
  const float* wv  = (const float*)d_in[20];
  const float* bv  = (const float*)d_in[21];
  const float* wp  = (const float*)d_in[22];
  const float* bp  = (const float*)d_in[23];
  const float* rel_h = (const float*)d_in[24];
  const float* rel_w = (const float*)d_in[25];
  const float* ef_h  = (const float*)d_in[26];
  const float* ef_w  = (const float*)d_in[27];
  float* outp = (float*)d_out;

  char* ws = (char*)d_ws;
  size_t off = 0;
  auto alloc = [&](size_t bytes) -> void* {
    void* p = ws + off;
    off += (bytes + 511) & ~(size_t)511;
    return p;
  };
  u16* xT    = (u16*)alloc((size_t)HW * 256 * 2);
  u16* x1T   = (u16*)alloc((size_t)HW * 128 * 2);
  u16* LT    = (u16*)alloc((size_t)HW * 256 * 2);
  u16* RT    = (u16*)alloc((size_t)HW * 256 * 2);
  u16* pT    = (u16*)alloc((size_t)HW * 128 * 2);
  u16* efT   = (u16*)alloc((size_t)HW * 128 * 2);
  u16* efc   = (u16*)alloc((size_t)HW * 128 * 2);
  u16* Vv    = (u16*)alloc((size_t)HW * 128 * 2);
  float* Opart = (float*)alloc((size_t)2 * 4 * HW * 128 * 4);  // 26.2 MB
  float* lpart = (float*)alloc((size_t)2 * 4 * HW * 4);
  u16* w1b   = (u16*)alloc(128 * 256 * 2);
  float* b1e = (float*)alloc(128 * 4);
  u16* Wcat  = (u16*)alloc(512 * 128 * 2);
  float* bcat = (float*)alloc(512 * 4);
  u16* w2b   = (u16*)alloc(256 * 128 * 2);
  float* b2e = (float*)alloc(256 * 4);
  u16* w3b   = (u16*)alloc(256 * 128 * 2);
  float* b3e = (float*)alloc(256 * 4);

  prep_all<<<944, 256, 0, stream>>>(x, rel_h, rel_w, ef_h, ef_w,
                                    w1, g1, b1, m1, v1, w2, g2, b2, m2, v2,
                                    w3, g3, b3, m3, v3, wq, bq, wk, bk, wv, bv, wp, bp,
                                    xT, LT, efT, efc,
                                    w1b, b1e, Wcat, bcat, w2b, b2e, w3b, b3e);
  gemm_x1<<<200, 128, 0, stream>>>(xT, w1b, b1e, x1T);
  gemm_qkvp<<<dim3(200, 4), 128, 0, stream>>>(x1T, Wcat, bcat, LT, RT, Vv, pT);
  attn_kernel<<<800, 256, 0, stream>>>(LT, RT, Vv, pT, efT, efc, Opart, lpart);
  final_k<<<dim3(100, 2), 256, 0, stream>>>(Opart, lpart, w2b, b2e, w3b, b3e, x, outp);
}

// Round 3
// 343.479 us; speedup vs baseline: 1.4161x; 1.4161x over previous
//
#include <hip/hip_runtime.h>

// ============================================================================
// ExtraMHSA pipeline for MI355X (gfx950).  R3: two-pass materialized-P.
//
//   prep_all : BN-fold weights->bf16, x transpose, pos embeds, zero O/l
//   gemm_x1  : x1T = silu(conv1(x))            [6400][128] bf16
//   gemm_qkvp: q,k,v,p -> LT/RT/V/pT layouts
//   score_k  : P = exp(L.R^T) bf16 [6400][6400] (no-max softmax: scores
//              bounded ~26), l[i] += rowsums (atomic). One barrier per block.
//   pv_k     : O[i][c] += P[i][:] . V^T (atomicAdd fp32), K split 10 ways.
//   final_k  : out = x + silu(bn(conv2(O1/l1))) + silu(bn(conv3(O2/l2)))
// Heads sequential: score(h1), pv(h1), score(h2), pv(h2) share one P buffer.
// ============================================================================

typedef unsigned short u16;
typedef __attribute__((ext_vector_type(8))) short bf16x8;   // 8 bf16 = 4 VGPRs
typedef __attribute__((ext_vector_type(4))) float f32x4;    // MFMA C/D frag
typedef __attribute__((ext_vector_type(4))) unsigned int u32x4;

#define HW 6400
#define BN_EPS 1e-5f

__device__ __forceinline__ u16 f2b(float f) {       // fp32 -> bf16 RNE
  unsigned u = __float_as_uint(f);
  u += 0x7fffu + ((u >> 16) & 1u);
  return (u16)(u >> 16);
}
__device__ __forceinline__ unsigned pack2(float a, float b) {
  return (unsigned)f2b(a) | ((unsigned)f2b(b) << 16);
}
__device__ __forceinline__ f32x4 MFMA(bf16x8 a, bf16x8 b, f32x4 c) {
  return __builtin_amdgcn_mfma_f32_16x16x32_bf16(a, b, c, 0, 0, 0);
}
__device__ __forceinline__ float silu_f(float y) {
  return y / (1.0f + __expf(-y));
}
__device__ __forceinline__ bf16x8 pack8(f32x4 lo, f32x4 hi, float sc) {
  union { bf16x8 v; uint4 u; } r;
  r.u.x = pack2(lo[0] * sc, lo[1] * sc);
  r.u.y = pack2(lo[2] * sc, lo[3] * sc);
  r.u.z = pack2(hi[0] * sc, hi[1] * sc);
  r.u.w = pack2(hi[2] * sc, hi[3] * sc);
  return r.v;
}

// ---------------------------------------------------------------------------
// prep_all: [0,800) xT transpose; [800,880) pos embeds; [880,944) weights;
//           [944,976) zero O and l.
// ---------------------------------------------------------------------------
__global__ void prep_all(
    const float* __restrict__ x,
    const float* __restrict__ rel_h, const float* __restrict__ rel_w,
    const float* __restrict__ ef_h, const float* __restrict__ ef_w,
    const float* __restrict__ w1, const float* __restrict__ g1, const float* __restrict__ b1,
    const float* __restrict__ m1, const float* __restrict__ v1,
    const float* __restrict__ w2, const float* __restrict__ g2, const float* __restrict__ b2,
    const float* __restrict__ m2, const float* __restrict__ v2,
    const float* __restrict__ w3, const float* __restrict__ g3, const float* __restrict__ b3,
    const float* __restrict__ m3, const float* __restrict__ v3,
    const float* __restrict__ wq, const float* __restrict__ bq,
    const float* __restrict__ wk, const float* __restrict__ bk,
    const float* __restrict__ wv, const float* __restrict__ bv,
    const float* __restrict__ wp, const float* __restrict__ bp,
    u16* __restrict__ xT,
    u16* __restrict__ LT, u16* __restrict__ efT, u16* __restrict__ efc,
    u16* __restrict__ w1b, float* __restrict__ b1e,
    u16* __restrict__ Wcat, float* __restrict__ bcat,
    u16* __restrict__ w2b, float* __restrict__ b2e,
    u16* __restrict__ w3b, float* __restrict__ b3e,
    float* __restrict__ Obuf, float* __restrict__ lbuf)
{
  __shared__ float tile[32][65];
  const int b = blockIdx.x;
  const int t = threadIdx.x;
  if (b < 800) {
    const int d0 = (b & 7) * 32;
    const int i0 = (b >> 3) * 64;
    {
      const int dr = t >> 3;
      const int ic = (t & 7) * 8;
      const float* src = x + (size_t)(d0 + dr) * HW + i0 + ic;
      f32x4 a = *(const f32x4*)src;
      f32x4 bb = *(const f32x4*)(src + 4);
#pragma unroll
      for (int e = 0; e < 4; ++e) { tile[dr][ic + e] = a[e]; tile[dr][ic + 4 + e] = bb[e]; }
    }
    __syncthreads();
    {
      const int ir = t >> 2;
      const int dc = (t & 3) * 8;
      uint4 u;
      u.x = pack2(tile[dc + 0][ir], tile[dc + 1][ir]);
      u.y = pack2(tile[dc + 2][ir], tile[dc + 3][ir]);
      u.z = pack2(tile[dc + 4][ir], tile[dc + 5][ir]);
      u.w = pack2(tile[dc + 6][ir], tile[dc + 7][ir]);
      *(uint4*)(xT + (size_t)(i0 + ir) * 256 + d0 + dc) = u;
    }
  } else if (b < 880) {
    const int h = b - 800;
    const int c0 = (t & 63) * 2;
    const float rh0 = rel_h[c0 * 80 + h], rh1 = rel_h[(c0 + 1) * 80 + h];
    const float eh0 = ef_h[c0 * 80 + h], eh1 = ef_h[(c0 + 1) * 80 + h];
    for (int wcol = (t >> 6); wcol < 80; wcol += 4) {
      const int i = h * 80 + wcol;
      float rw0 = rel_w[c0 * 80 + wcol], rw1 = rel_w[(c0 + 1) * 80 + wcol];
      float ew0 = ef_w[c0 * 80 + wcol], ew1 = ef_w[(c0 + 1) * 80 + wcol];
      *(unsigned*)&LT[(size_t)i * 256 + 128 + c0] = pack2(rh0 + rw0, rh1 + rw1);
      float e0 = eh0 + ew0, e1 = eh1 + ew1;
      *(unsigned*)&efT[(size_t)i * 128 + c0] = pack2(e0, e1);
      efc[(size_t)c0 * HW + i] = f2b(e0);
      efc[(size_t)(c0 + 1) * HW + i] = f2b(e1);
    }
  } else if (b < 944) {
    const int tid = (b - 880) * 256 + t;
    const int stride = 64 * 256;
    for (int idx = tid; idx < 128 * 256; idx += stride) {
      int o = idx >> 8;
      float s = g1[o] * rsqrtf(v1[o] + BN_EPS);
      w1b[idx] = f2b(w1[idx] * s);
    }
    for (int idx = tid; idx < 128; idx += stride) {
      float s = g1[idx] * rsqrtf(v1[idx] + BN_EPS);
      b1e[idx] = b1[idx] - m1[idx] * s;
    }
    for (int idx = tid; idx < 4 * 128 * 128; idx += stride) {
      int which = idx >> 14, r = idx & 16383;
      const float* src = which == 0 ? wq : which == 1 ? wk : which == 2 ? wv : wp;
      Wcat[idx] = f2b(src[r]);
    }
    for (int idx = tid; idx < 512; idx += stride) {
      int which = idx >> 7, r = idx & 127;
      const float* src = which == 0 ? bq : which == 1 ? bk : which == 2 ? bv : bp;
      bcat[idx] = src[r];
    }
    for (int idx = tid; idx < 256 * 128; idx += stride) {
      int o = idx >> 7;
      float s2 = g2[o] * rsqrtf(v2[o] + BN_EPS);
      w2b[idx] = f2b(w2[idx] * s2);
      float s3 = g3[o] * rsqrtf(v3[o] + BN_EPS);
      w3b[idx] = f2b(w3[idx] * s3);
    }
    for (int idx = tid; idx < 256; idx += stride) {
      float s2 = g2[idx] * rsqrtf(v2[idx] + BN_EPS);
      b2e[idx] = b2[idx] - m2[idx] * s2;
      float s3 = g3[idx] * rsqrtf(v3[idx] + BN_EPS);
      b3e[idx] = b3[idx] - m3[idx] * s3;
    }
  } else {
    // zero O [2][HW][128] and l [2][HW]
    const int tid = (b - 944) * 256 + t;
    const int stride = 32 * 256;
    f32x4 z = {0.f, 0.f, 0.f, 0.f};
    for (int idx = tid; idx < 2 * HW * 128 / 4; idx += stride)
      ((f32x4*)Obuf)[idx] = z;
    for (int idx = tid; idx < 2 * HW / 4; idx += stride)
      ((f32x4*)lbuf)[idx] = z;
  }
}

// ---------------------------------------------------------------------------
// gemm_x1: x1T[i][c] = silu(xT[i][:] . w1b[c][:] + b1e[c]).  K=256, N=128.
// grid <<<100, 256>>>; 4 waves x 16 rows.
// ---------------------------------------------------------------------------
__global__ __launch_bounds__(256) void gemm_x1(
    const u16* __restrict__ xT, const u16* __restrict__ w1b,
    const float* __restrict__ b1e, u16* __restrict__ x1T)
{
  __shared__ __align__(16) u16 tr[4][16][136];
  const int t = threadIdx.x, w = t >> 6, lane = t & 63, jl = lane & 15, q = lane >> 4;
  const int i0 = blockIdx.x * 64 + w * 16;
  f32x4 acc[8];
#pragma unroll
  for (int nf = 0; nf < 8; ++nf) acc[nf] = (f32x4){0.f, 0.f, 0.f, 0.f};
#pragma unroll
  for (int ks = 0; ks < 8; ++ks) {
    bf16x8 a = *(const bf16x8*)(xT + (size_t)(i0 + jl) * 256 + ks * 32 + q * 8);
#pragma unroll
    for (int nf = 0; nf < 8; ++nf) {
      bf16x8 b = *(const bf16x8*)(w1b + (size_t)(nf * 16 + jl) * 256 + ks * 32 + q * 8);
      acc[nf] = MFMA(a, b, acc[nf]);
    }
  }
#pragma unroll
  for (int nf = 0; nf < 8; ++nf) {
    const int c = nf * 16 + jl;
    const float bias = b1e[c];
#pragma unroll
    for (int r = 0; r < 4; ++r)
      tr[w][q * 4 + r][c] = f2b(silu_f(acc[nf][r] + bias));
  }
  __syncthreads();
#pragma unroll
  for (int r = 0; r < 16; ++r) {
    unsigned val = *(const unsigned*)&tr[w][r][lane * 2];
    *(unsigned*)(x1T + (size_t)(i0 + r) * 128 + lane * 2) = val;
  }
}

// ---------------------------------------------------------------------------
// gemm_qkvp: [q|k|v|p] = x1T . Wcat^T + bcat, routed into attention layouts.
// grid dim3(100, 4), 256 thr.
// ---------------------------------------------------------------------------
__global__ __launch_bounds__(256) void gemm_qkvp(
    const u16* __restrict__ x1T, const u16* __restrict__ Wcat, const float* __restrict__ bcat,
    u16* __restrict__ LT, u16* __restrict__ RT, u16* __restrict__ Vv, u16* __restrict__ pT)
{
  __shared__ __align__(16) u16 tr[4][16][136];
  const int t = threadIdx.x, w = t >> 6, lane = t & 63, jl = lane & 15, q = lane >> 4;
  const int i0 = blockIdx.x * 64 + w * 16;
  const int nc = blockIdx.y;
  f32x4 acc[8];
#pragma unroll
  for (int nf = 0; nf < 8; ++nf) acc[nf] = (f32x4){0.f, 0.f, 0.f, 0.f};
#pragma unroll
  for (int ks = 0; ks < 4; ++ks) {
    bf16x8 a = *(const bf16x8*)(x1T + (size_t)(i0 + jl) * 128 + ks * 32 + q * 8);
#pragma unroll
    for (int nf = 0; nf < 8; ++nf) {
      bf16x8 b = *(const bf16x8*)(Wcat + (size_t)(nc * 128 + nf * 16 + jl) * 128 + ks * 32 + q * 8);
      acc[nf] = MFMA(a, b, acc[nf]);
    }
  }
  if (nc == 2) {                                 // V: [c][i] c-major, direct
#pragma unroll
    for (int nf = 0; nf < 8; ++nf) {
      const int c = nf * 16 + jl;
      const float bias = bcat[256 + c];
      uint2 pk;
      pk.x = pack2(acc[nf][0] + bias, acc[nf][1] + bias);
      pk.y = pack2(acc[nf][2] + bias, acc[nf][3] + bias);
      *(uint2*)(Vv + (size_t)c * HW + i0 + q * 4) = pk;
    }
  } else {
#pragma unroll
    for (int nf = 0; nf < 8; ++nf) {
      const int c = nf * 16 + jl;
      const float bias = bcat[nc * 128 + c];
#pragma unroll
      for (int r = 0; r < 4; ++r)
        tr[w][q * 4 + r][c] = f2b(acc[nf][r] + bias);
    }
    __syncthreads();
#pragma unroll
    for (int r = 0; r < 16; ++r) {
      unsigned val = *(const unsigned*)&tr[w][r][lane * 2];
      const size_t row = (size_t)(i0 + r);
      if (nc == 0) {
        *(unsigned*)(LT + row * 256 + lane * 2) = val;
        *(unsigned*)(RT + row * 256 + 128 + lane * 2) = val;
      } else if (nc == 1) {
        *(unsigned*)(RT + row * 256 + lane * 2) = val;
      } else {
        *(unsigned*)(pT + row * 128 + lane * 2) = val;
      }
    }
  }
}

// ---------------------------------------------------------------------------
// score_k: P[i][j] = exp(Lt[i][:] . Rt[j][:]) bf16; l[i] += rowsum (atomic).
// Block = 128i x 128j tile; 4 waves x 32 i-rows (mt=2); B-tile in LDS staged
// ONCE (single barrier). grid <<<2500, 256>>>.
// ---------------------------------------------------------------------------
template <int KD>
__global__ __launch_bounds__(256, 2) void score_k(
    const u16* __restrict__ Lt,     // [HW][KD]
    const u16* __restrict__ Rt,     // [HW][KD]
    u16* __restrict__ P,            // [HW][HW] bf16 row-major
    float* __restrict__ lv)         // [HW]
{
  __shared__ __align__(16) u16 Bs[128 * KD];     // 64KB (KD=256) / 32KB (128)
  const int t = threadIdx.x, w = t >> 6, lane = t & 63, jl = lane & 15, q = lane >> 4;
  const int it = blockIdx.x / 50, jt = blockIdx.x % 50;
  const int i0 = it * 128 + w * 32;
  const int jb0 = jt * 128;
  constexpr int NKS = KD / 32;

  // A fragments resident in registers (2 m-tiles x K)
  bf16x8 afr[2][NKS];
#pragma unroll
  for (int mt = 0; mt < 2; ++mt)
#pragma unroll
    for (int ks = 0; ks < NKS; ++ks)
      afr[mt][ks] = *(const bf16x8*)(Lt + (size_t)(i0 + mt * 16 + jl) * KD + ks * 32 + q * 8);

  // Stage B tile [128 j][KD] with XOR-8 16B-chunk swizzle
  if constexpr (KD == 256) {
#pragma unroll
    for (int cc = 0; cc < 16; ++cc) {
      int jr = w * 32 + cc * 2 + (lane >> 5);
      int cp = lane & 31;
      int ch = (cp & ~7) | ((cp ^ jr) & 7);
      *(u32x4*)(Bs + jr * 256 + cp * 8) =
          *(const u32x4*)(Rt + (size_t)(jb0 + jr) * 256 + ch * 8);
    }
  } else {
#pragma unroll
    for (int cc = 0; cc < 8; ++cc) {
      int jr = w * 32 + cc * 4 + (lane >> 4);
      int cp = lane & 15;
      int ch = (cp & ~7) | ((cp ^ jr) & 7);
      *(u32x4*)(Bs + jr * 128 + cp * 8) =
          *(const u32x4*)(Rt + (size_t)(jb0 + jr) * 128 + ch * 8);
    }
  }
  __syncthreads();                               // the ONLY barrier

  f32x4 s[2][8];
#pragma unroll
  for (int mt = 0; mt < 2; ++mt)
#pragma unroll
    for (int nf = 0; nf < 8; ++nf) s[mt][nf] = (f32x4){0.f, 0.f, 0.f, 0.f};

#pragma unroll
  for (int nf = 0; nf < 8; ++nf) {
    const int row = nf * 16 + jl;
#pragma unroll
    for (int ks = 0; ks < NKS; ++ks) {
      const int ch = (ks * 4 + q) ^ (jl & 7);    // un-swizzle
      bf16x8 b = *(const bf16x8*)(Bs + row * KD + ch * 8);
      s[0][nf] = MFMA(afr[0][ks], b, s[0][nf]);
      s[1][nf] = MFMA(afr[1][ks], b, s[1][nf]);
    }
  }

  // exp, row-sum (atomic into lv), bf16 store of P
#pragma unroll
  for (int mt = 0; mt < 2; ++mt) {
    float rs[4] = {0.f, 0.f, 0.f, 0.f};
#pragma unroll
    for (int nf = 0; nf < 8; ++nf)
#pragma unroll
      for (int r = 0; r < 4; ++r) {
        float p = __expf(s[mt][nf][r]);
        s[mt][nf][r] = p;
        rs[r] += p;
      }
#pragma unroll
    for (int d = 1; d < 16; d <<= 1)
#pragma unroll
      for (int r = 0; r < 4; ++r) rs[r] += __shfl_xor(rs[r], d);
    if (jl == 0) {
#pragma unroll
      for (int r = 0; r < 4; ++r)
        atomicAdd(&lv[i0 + mt * 16 + q * 4 + r], rs[r]);
    }
#pragma unroll
    for (int nf = 0; nf < 8; ++nf)
#pragma unroll
      for (int r = 0; r < 4; ++r)
        P[(size_t)(i0 + mt * 16 + q * 4 + r) * HW + jb0 + nf * 16 + jl] =
            f2b(s[mt][nf][r]);
  }
}

// ---------------------------------------------------------------------------
// pv_k: O[i][c] += sum_j P[i][j] * Vm[c][j]  (fp32 atomicAdd).
// Block = 64i x 128c, K-range = 640 j (jp 0..9), chunks of 64 j.
// 4 waves: wave tile 32i x 64c. LDS 24KB -> 6 blocks/CU. grid <<<1000, 256>>>.
// ---------------------------------------------------------------------------
__global__ __launch_bounds__(256) void pv_k(
    const u16* __restrict__ P,      // [HW][HW]
    const u16* __restrict__ Vm,     // [128][HW]
    float* __restrict__ O)          // [HW][128]
{
  __shared__ __align__(16) u16 As[64 * 64];      // 8KB
  __shared__ __align__(16) u16 Bs[128 * 64];     // 16KB
  const int t = threadIdx.x, w = t >> 6, lane = t & 63, jl = lane & 15, q = lane >> 4;
  const int it = blockIdx.x / 10, jp = blockIdx.x % 10;
  const int i0 = it * 64, jbase = jp * 640;
  const int iw = (w & 1) * 32, cw = (w >> 1) * 64;

  f32x4 o[2][4];
#pragma unroll
  for (int mt = 0; mt < 2; ++mt)
#pragma unroll
    for (int cf = 0; cf < 4; ++cf) o[mt][cf] = (f32x4){0.f, 0.f, 0.f, 0.f};

  for (int stp = 0; stp < 10; ++stp) {
    const int jj = jbase + stp * 64;
    __syncthreads();
    // stage As [64 i][64 j]: 512 16B-chunks, 2/thread, linear LDS writes
#pragma unroll
    for (int k = 0; k < 2; ++k) {
      int cidx = t + k * 256;
      int row = cidx >> 3, cp = cidx & 7;
      int ch = cp ^ (row & 7);
      *(u32x4*)(As + cidx * 8) =
          *(const u32x4*)(P + (size_t)(i0 + row) * HW + jj + ch * 8);
    }
    // stage Bs [128 c][64 j]: 1024 chunks, 4/thread
#pragma unroll
    for (int k = 0; k < 4; ++k) {
      int cidx = t + k * 256;
      int row = cidx >> 3, cp = cidx & 7;
      int ch = cp ^ (row & 7);
      *(u32x4*)(Bs + cidx * 8) =
          *(const u32x4*)(Vm + (size_t)row * HW + jj + ch * 8);
    }
    __syncthreads();
#pragma unroll
    for (int ks2 = 0; ks2 < 2; ++ks2) {
      const int ch = ((ks2 * 4 + q) ^ (jl & 7)) * 8;
      bf16x8 a0 = *(const bf16x8*)(As + (iw + jl) * 64 + ch);
      bf16x8 a1 = *(const bf16x8*)(As + (iw + 16 + jl) * 64 + ch);
#pragma unroll
      for (int cf = 0; cf < 4; ++cf) {
        bf16x8 b = *(const bf16x8*)(Bs + (cw + cf * 16 + jl) * 64 + ch);
        o[0][cf] = MFMA(a0, b, o[0][cf]);
        o[1][cf] = MFMA(a1, b, o[1][cf]);
      }
    }
  }
  // epilogue: atomic accumulate into O
#pragma unroll
  for (int mt = 0; mt < 2; ++mt) {
    const int ib = i0 + iw + mt * 16 + q * 4;
#pragma unroll
    for (int cf = 0; cf < 4; ++cf) {
      const int c = cw + cf * 16 + jl;
#pragma unroll
      for (int r = 0; r < 4; ++r)
        atomicAdd(&O[(size_t)(ib + r) * 128 + c], o[mt][cf][r]);
    }
  }
}

// ---------------------------------------------------------------------------
// final_k: out[d][i] = x[d][i] + silu(o1.w2b + b2e) + silu(o2.w3b + b3e),
// o?[i][c] = O[h][i][c] / l[h][i], built as bf16 A-frags on the fly.
// grid dim3(100, 2), 256 thr.
// ---------------------------------------------------------------------------
__global__ __launch_bounds__(256) void final_k(
    const float* __restrict__ Obuf,    // [2][HW][128]
    const float* __restrict__ lbuf,    // [2][HW]
    const u16* __restrict__ w2b, const float* __restrict__ b2e,
    const u16* __restrict__ w3b, const float* __restrict__ b3e,
    const float* __restrict__ x, float* __restrict__ outp)
{
  const int t = threadIdx.x, w = t >> 6, lane = t & 63, jl = lane & 15, q = lane >> 4;
  const int i0 = blockIdx.x * 64 + w * 16;
  const int nc = blockIdx.y;
  const int row = i0 + jl;

  const float inv1 = 1.0f / lbuf[row];
  const float inv2 = 1.0f / lbuf[HW + row];
  const float* O1 = Obuf + (size_t)row * 128;
  const float* O2 = Obuf + (size_t)(HW + row) * 128;

  f32x4 a1[8], a2[8];
#pragma unroll
  for (int nf = 0; nf < 8; ++nf) {
    a1[nf] = (f32x4){0.f, 0.f, 0.f, 0.f};
    a2[nf] = (f32x4){0.f, 0.f, 0.f, 0.f};
  }
#pragma unroll
  for (int ks = 0; ks < 4; ++ks) {
    f32x4 s1a = *(const f32x4*)(O1 + ks * 32 + q * 8);
    f32x4 s1b = *(const f32x4*)(O1 + ks * 32 + q * 8 + 4);
    f32x4 s2a = *(const f32x4*)(O2 + ks * 32 + q * 8);
    f32x4 s2b = *(const f32x4*)(O2 + ks * 32 + q * 8 + 4);
    bf16x8 fa1 = pack8(s1a, s1b, inv1);
    bf16x8 fa2 = pack8(s2a, s2b, inv2);
#pragma unroll
    for (int nf = 0; nf < 8; ++nf) {
      bf16x8 b2f = *(const bf16x8*)(w2b + (size_t)(nc * 128 + nf * 16 + jl) * 128 + ks * 32 + q * 8);
      bf16x8 b3f = *(const bf16x8*)(w3b + (size_t)(nc * 128 + nf * 16 + jl) * 128 + ks * 32 + q * 8);
      a1[nf] = MFMA(fa1, b2f, a1[nf]);
      a2[nf] = MFMA(fa2, b3f, a2[nf]);
    }
  }
#pragma unroll
  for (int nf = 0; nf < 8; ++nf) {
    const int d = nc * 128 + nf * 16 + jl;
    const float bb2 = b2e[d], bb3 = b3e[d];
    const size_t base = (size_t)d * HW + i0 + q * 4;
    f32x4 xv = *(const f32x4*)(x + base);
    f32x4 rv;
#pragma unroll
    for (int r = 0; r < 4; ++r)
      rv[r] = xv[r] + silu_f(a1[nf][r] + bb2) + silu_f(a2[nf][r] + bb3);
    *(f32x4*)(outp + base) = rv;
  }
}

// ---------------------------------------------------------------------------
extern "C" void kernel_launch(void* const* d_in, const int* in_sizes, int n_in,
                              void* d_out, int out_size, void* d_ws, size_t ws_size,
                              hipStream_t stream)
{
  (void)in_sizes; (void)n_in; (void)out_size; (void)ws_size;
  const float* x   = (const float*)d_in[0];
  const float* w1  = (const float*)d_in[1];
  const float* g1  = (const float*)d_in[2];
  const float* b1  = (const float*)d_in[3];
  const float* m1  = (const float*)d_in[4];
  const float* v1  = (const float*)d_in[5];
  const float* w2  = (const float*)d_in[6];
  const float* g2  = (const float*)d_in[7];
  const float* b2  = (const float*)d_in[8];
  const float* m2  = (const float*)d_in[9];
  const float* v2  = (const float*)d_in[10];
  const float* w3  = (const float*)d_in[11];
  const float* g3  = (const float*)d_in[12];
  const float* b3  = (const float*)d_in[13];
  const float* m3  = (const float*)d_in[14];
  const float* v3  = (const float*)d_in[15];
  const float* wq  = (const float*)d_in[16];
  const float* bq  = (const float*)d_in[17];
  const float* wk  = (const float*)d_in[18];
  const float* bk  = (const float*)d_in[19];
  const float* wv  = (const float*)d_in[20];
  const float* bv  = (const float*)d_in[21];
  const float* wp  = (const float*)d_in[22];
  const float* bp  = (const float*)d_in[23];
  const float* rel_h = (const float*)d_in[24];
  const float* rel_w = (const float*)d_in[25];
  const float* ef_h  = (const float*)d_in[26];
  const float* ef_w  = (const float*)d_in[27];
  float* outp = (float*)d_out;

  char* ws = (char*)d_ws;
  size_t off = 0;
  auto alloc = [&](size_t bytes) -> void* {
    void* p = ws + off;
    off += (bytes + 511) & ~(size_t)511;
    return p;
  };
  u16* xT    = (u16*)alloc((size_t)HW * 256 * 2);
  u16* x1T   = (u16*)alloc((size_t)HW * 128 * 2);
  u16* LT    = (u16*)alloc((size_t)HW * 256 * 2);
  u16* RT    = (u16*)alloc((size_t)HW * 256 * 2);
  u16* pT    = (u16*)alloc((size_t)HW * 128 * 2);
  u16* efT   = (u16*)alloc((size_t)HW * 128 * 2);
  u16* efc   = (u16*)alloc((size_t)HW * 128 * 2);
  u16* Vv    = (u16*)alloc((size_t)HW * 128 * 2);
  u16* Pbuf  = (u16*)alloc((size_t)HW * HW * 2);            // 81.9 MB, reused per head
  float* Obuf = (float*)alloc((size_t)2 * HW * 128 * 4);    // 6.55 MB
  float* lbuf = (float*)alloc((size_t)2 * HW * 4);
  u16* w1b   = (u16*)alloc(128 * 256 * 2);
  float* b1e = (float*)alloc(128 * 4);
  u16* Wcat  = (u16*)alloc(512 * 128 * 2);
  float* bcat = (float*)alloc(512 * 4);
  u16* w2b   = (u16*)alloc(256 * 128 * 2);
  float* b2e = (float*)alloc(256 * 4);
  u16* w3b   = (u16*)alloc(256 * 128 * 2);
  float* b3e = (float*)alloc(256 * 4);

  prep_all<<<976, 256, 0, stream>>>(x, rel_h, rel_w, ef_h, ef_w,
                                    w1, g1, b1, m1, v1, w2, g2, b2, m2, v2,
                                    w3, g3, b3, m3, v3, wq, bq, wk, bk, wv, bv, wp, bp,
                                    xT, LT, efT, efc,
                                    w1b, b1e, Wcat, bcat, w2b, b2e, w3b, b3e,
                                    Obuf, lbuf);
  gemm_x1<<<100, 256, 0, stream>>>(xT, w1b, b1e, x1T);
  gemm_qkvp<<<dim3(100, 4), 256, 0, stream>>>(x1T, Wcat, bcat, LT, RT, Vv, pT);
  // head 1
  score_k<256><<<2500, 256, 0, stream>>>(LT, RT, Pbuf, lbuf);
  pv_k<<<1000, 256, 0, stream>>>(Pbuf, Vv, Obuf);
  // head 2 (reuses Pbuf)
  score_k<128><<<2500, 256, 0, stream>>>(pT, efT, Pbuf, lbuf + HW);
  pv_k<<<1000, 256, 0, stream>>>(Pbuf, efc, Obuf + (size_t)HW * 128);
  final_k<<<dim3(100, 2), 256, 0, stream>>>(Obuf, lbuf, w2b, b2e, w3b, b3e, x, outp);
}

// Round 5
// 340.319 us; speedup vs baseline: 1.4293x; 1.0093x over previous
//
#include <hip/hip_runtime.h>

// ============================================================================
// ExtraMHSA pipeline for MI355X (gfx950).  R5: R4 + wave-LDS ordering fixes.
//
//   prep_all : pos embeds, BN-fold weights->bf16, zero O/l
//   front_k  : x ->(regs) x1=silu(conv1) ->(LDS) q,k,v,p -> LT/RT/Vv/pT
//   score_k  : P = exp(L.R^T) (no-max softmax: scores bounded ~26),
//              l[i] += rowsum (atomic). P stored in pv-A-frag TILED layout
//              ([j/64][i/16] tiles of 16x64 row-major) w/ coalesced stores.
//   pv_k     : O[i][c] += P.V^T; A-frags DIRECT from global tiled P,
//              V staged in LDS; fp32 atomicAdd into O.
//   final_k  : out = x + silu(bn(conv2(O1/l1))) + silu(bn(conv3(O2/l2)))
//
// R4 bug: LDS write->read handoffs (tr/T16) had no barrier; per-lane alias
// analysis sees no dependency (lane writes rows q*4+r, reads row jl) so the
// compiler may hoist ds_read above ds_write -> stale cross-lane data.
// Fix: __syncthreads() around every LDS handoff phase (loop-uniform).
// ============================================================================

typedef unsigned short u16;
typedef __attribute__((ext_vector_type(8))) short bf16x8;   // 8 bf16 = 4 VGPRs
typedef __attribute__((ext_vector_type(4))) float f32x4;    // MFMA C/D frag
typedef __attribute__((ext_vector_type(4))) unsigned int u32x4;

#define HW 6400
#define BN_EPS 1e-5f

__device__ __forceinline__ u16 f2b(float f) {       // fp32 -> bf16 RNE
  unsigned u = __float_as_uint(f);
  u += 0x7fffu + ((u >> 16) & 1u);
  return (u16)(u >> 16);
}
__device__ __forceinline__ unsigned pack2(float a, float b) {
  return (unsigned)f2b(a) | ((unsigned)f2b(b) << 16);
}
__device__ __forceinline__ f32x4 MFMA(bf16x8 a, bf16x8 b, f32x4 c) {
  return __builtin_amdgcn_mfma_f32_16x16x32_bf16(a, b, c, 0, 0, 0);
}
__device__ __forceinline__ float silu_f(float y) {
  return y / (1.0f + __expf(-y));
}
__device__ __forceinline__ bf16x8 pack8(f32x4 lo, f32x4 hi, float sc) {
  union { bf16x8 v; uint4 u; } r;
  r.u.x = pack2(lo[0] * sc, lo[1] * sc);
  r.u.y = pack2(lo[2] * sc, lo[3] * sc);
  r.u.z = pack2(hi[0] * sc, hi[1] * sc);
  r.u.w = pack2(hi[2] * sc, hi[3] * sc);
  return r.v;
}

// ---------------------------------------------------------------------------
// prep_all: [0,80) pos embeds; [80,144) weight BN-fold; [144,176) zero O/l.
// ---------------------------------------------------------------------------
__global__ void prep_all(
    const float* __restrict__ rel_h, const float* __restrict__ rel_w,
    const float* __restrict__ ef_h, const float* __restrict__ ef_w,
    const float* __restrict__ w1, const float* __restrict__ g1, const float* __restrict__ b1,
    const float* __restrict__ m1, const float* __restrict__ v1,
    const float* __restrict__ w2, const float* __restrict__ g2, const float* __restrict__ b2,
    const float* __restrict__ m2, const float* __restrict__ v2,
    const float* __restrict__ w3, const float* __restrict__ g3, const float* __restrict__ b3,
    const float* __restrict__ m3, const float* __restrict__ v3,
    const float* __restrict__ wq, const float* __restrict__ bq,
    const float* __restrict__ wk, const float* __restrict__ bk,
    const float* __restrict__ wv, const float* __restrict__ bv,
    const float* __restrict__ wp, const float* __restrict__ bp,
    u16* __restrict__ LT, u16* __restrict__ efT, u16* __restrict__ efc,
    u16* __restrict__ w1b, float* __restrict__ b1e,
    u16* __restrict__ Wcat, float* __restrict__ bcat,
    u16* __restrict__ w2b, float* __restrict__ b2e,
    u16* __restrict__ w3b, float* __restrict__ b3e,
    float* __restrict__ Obuf, float* __restrict__ lbuf)
{
  const int b = blockIdx.x;
  const int t = threadIdx.x;
  if (b < 80) {
    const int h = b;
    const int c0 = (t & 63) * 2;
    const float rh0 = rel_h[c0 * 80 + h], rh1 = rel_h[(c0 + 1) * 80 + h];
    const float eh0 = ef_h[c0 * 80 + h], eh1 = ef_h[(c0 + 1) * 80 + h];
    for (int wcol = (t >> 6); wcol < 80; wcol += 4) {
      const int i = h * 80 + wcol;
      float rw0 = rel_w[c0 * 80 + wcol], rw1 = rel_w[(c0 + 1) * 80 + wcol];
      float ew0 = ef_w[c0 * 80 + wcol], ew1 = ef_w[(c0 + 1) * 80 + wcol];
      *(unsigned*)&LT[(size_t)i * 256 + 128 + c0] = pack2(rh0 + rw0, rh1 + rw1);
      float e0 = eh0 + ew0, e1 = eh1 + ew1;
      *(unsigned*)&efT[(size_t)i * 128 + c0] = pack2(e0, e1);
      efc[(size_t)c0 * HW + i] = f2b(e0);
      efc[(size_t)(c0 + 1) * HW + i] = f2b(e1);
    }
  } else if (b < 144) {
    const int tid = (b - 80) * 256 + t;
    const int stride = 64 * 256;
    for (int idx = tid; idx < 128 * 256; idx += stride) {
      int o = idx >> 8;
      float s = g1[o] * rsqrtf(v1[o] + BN_EPS);
      w1b[idx] = f2b(w1[idx] * s);
    }
    for (int idx = tid; idx < 128; idx += stride) {
      float s = g1[idx] * rsqrtf(v1[idx] + BN_EPS);
      b1e[idx] = b1[idx] - m1[idx] * s;
    }
    for (int idx = tid; idx < 4 * 128 * 128; idx += stride) {
      int which = idx >> 14, r = idx & 16383;
      const float* src = which == 0 ? wq : which == 1 ? wk : which == 2 ? wv : wp;
      Wcat[idx] = f2b(src[r]);
    }
    for (int idx = tid; idx < 512; idx += stride) {
      int which = idx >> 7, r = idx & 127;
      const float* src = which == 0 ? bq : which == 1 ? bk : which == 2 ? bv : bp;
      bcat[idx] = src[r];
    }
    for (int idx = tid; idx < 256 * 128; idx += stride) {
      int o = idx >> 7;
      float s2 = g2[o] * rsqrtf(v2[o] + BN_EPS);
      w2b[idx] = f2b(w2[idx] * s2);
      float s3 = g3[o] * rsqrtf(v3[o] + BN_EPS);
      w3b[idx] = f2b(w3[idx] * s3);
    }
    for (int idx = tid; idx < 256; idx += stride) {
      float s2 = g2[idx] * rsqrtf(v2[idx] + BN_EPS);
      b2e[idx] = b2[idx] - m2[idx] * s2;
      float s3 = g3[idx] * rsqrtf(v3[idx] + BN_EPS);
      b3e[idx] = b3[idx] - m3[idx] * s3;
    }
  } else {
    const int tid = (b - 144) * 256 + t;
    const int stride = 32 * 256;
    f32x4 z = {0.f, 0.f, 0.f, 0.f};
    for (int idx = tid; idx < 2 * HW * 128 / 4; idx += stride)
      ((f32x4*)Obuf)[idx] = z;
    for (int idx = tid; idx < 2 * HW / 4; idx += stride)
      ((f32x4*)lbuf)[idx] = z;
  }
}

// ---------------------------------------------------------------------------
// front_k: fused  x -> x1=silu(bn(conv1(x))) -> {q,k,v,p} -> LT/RT/Vv/pT.
// grid <<<200, 128>>>: 2 waves x 16 i-rows. Barriers guard every LDS
// write->read handoff (uniform across the block).
// ---------------------------------------------------------------------------
__global__ __launch_bounds__(128) void front_k(
    const float* __restrict__ x,
    const u16* __restrict__ w1b, const float* __restrict__ b1e,
    const u16* __restrict__ Wcat, const float* __restrict__ bcat,
    u16* __restrict__ LT, u16* __restrict__ RT, u16* __restrict__ Vv,
    u16* __restrict__ pT)
{
  __shared__ __align__(16) u16 tr[2][16][136];
  const int t = threadIdx.x, w = t >> 6, lane = t & 63, jl = lane & 15, q = lane >> 4;
  const int i0 = blockIdx.x * 32 + w * 16;

  // ---- x A-fragments (k = channel d), built from strided fp32 loads
  bf16x8 afr[8];
#pragma unroll
  for (int ks = 0; ks < 8; ++ks) {
    union { bf16x8 v; u16 e[8]; } fa;
#pragma unroll
    for (int e = 0; e < 8; ++e)
      fa.e[e] = f2b(x[(size_t)(ks * 32 + q * 8 + e) * HW + i0 + jl]);
    afr[ks] = fa.v;
  }
  // ---- x1 = silu(x . w1b + b1e)
  f32x4 acc[8];
#pragma unroll
  for (int nf = 0; nf < 8; ++nf) acc[nf] = (f32x4){0.f, 0.f, 0.f, 0.f};
#pragma unroll
  for (int ks = 0; ks < 8; ++ks)
#pragma unroll
    for (int nf = 0; nf < 8; ++nf) {
      bf16x8 b = *(const bf16x8*)(w1b + (size_t)(nf * 16 + jl) * 256 + ks * 32 + q * 8);
      acc[nf] = MFMA(afr[ks], b, acc[nf]);
    }
#pragma unroll
  for (int nf = 0; nf < 8; ++nf) {
    const int c = nf * 16 + jl;
    const float bias = b1e[c];
#pragma unroll
    for (int r = 0; r < 4; ++r)
      tr[w][q * 4 + r][c] = f2b(silu_f(acc[nf][r] + bias));
  }
  __syncthreads();                               // x1 writes -> xa reads
  bf16x8 xa[4];
#pragma unroll
  for (int ks = 0; ks < 4; ++ks)
    xa[ks] = *(const bf16x8*)&tr[w][jl][ks * 32 + q * 8];

  // ---- q,k,v,p projections
#pragma unroll
  for (int nc = 0; nc < 4; ++nc) {
    f32x4 a2[8];
#pragma unroll
    for (int nf = 0; nf < 8; ++nf) a2[nf] = (f32x4){0.f, 0.f, 0.f, 0.f};
#pragma unroll
    for (int ks = 0; ks < 4; ++ks)
#pragma unroll
      for (int nf = 0; nf < 8; ++nf) {
        bf16x8 b = *(const bf16x8*)(Wcat + (size_t)(nc * 128 + nf * 16 + jl) * 128 + ks * 32 + q * 8);
        a2[nf] = MFMA(xa[ks], b, a2[nf]);
      }
    if (nc == 2) {                               // V: [c][i] direct store
#pragma unroll
      for (int nf = 0; nf < 8; ++nf) {
        const int c = nf * 16 + jl;
        const float bias = bcat[256 + c];
        uint2 pk;
        pk.x = pack2(a2[nf][0] + bias, a2[nf][1] + bias);
        pk.y = pack2(a2[nf][2] + bias, a2[nf][3] + bias);
        *(uint2*)(Vv + (size_t)c * HW + i0 + q * 4) = pk;
      }
    } else {
      __syncthreads();                           // prev reads done -> overwrite
#pragma unroll
      for (int nf = 0; nf < 8; ++nf) {
        const int c = nf * 16 + jl;
        const float bias = bcat[nc * 128 + c];
#pragma unroll
        for (int r = 0; r < 4; ++r)
          tr[w][q * 4 + r][c] = f2b(a2[nf][r] + bias);
      }
      __syncthreads();                           // writes -> row reads
#pragma unroll
      for (int r = 0; r < 16; ++r) {
        unsigned val = *(const unsigned*)&tr[w][r][lane * 2];
        const size_t row = (size_t)(i0 + r);
        if (nc == 0) {
          *(unsigned*)(LT + row * 256 + lane * 2) = val;
          *(unsigned*)(RT + row * 256 + 128 + lane * 2) = val;
        } else if (nc == 1) {
          *(unsigned*)(RT + row * 256 + lane * 2) = val;
        } else {
          *(unsigned*)(pT + row * 128 + lane * 2) = val;
        }
      }
    }
  }
}

// ---------------------------------------------------------------------------
// score_k: P = exp(Lt . Rt^T) into TILED layout; l[i] += rowsum (atomic).
// Block = 128i x 128j; 4 waves x 32i (mt=2). B-tile staged once in LDS.
// Tiled P: tile (jt=j/64, it16=i/16), 1024 elems, [16 i][64 j] row-major.
// grid <<<2500, 256>>>.
// ---------------------------------------------------------------------------
template <int KD, int MINB>
__global__ __launch_bounds__(256, MINB) void score_k(
    const u16* __restrict__ Lt,     // [HW][KD]
    const u16* __restrict__ Rt,     // [HW][KD]
    u16* __restrict__ P,            // tiled
    float* __restrict__ lv)         // [HW]
{
  __shared__ __align__(16) u16 Bs[128 * KD];     // 64KB (KD=256) / 32KB (128)
  const int t = threadIdx.x, w = t >> 6, lane = t & 63, jl = lane & 15, q = lane >> 4;
  const int it = blockIdx.x / 50, jt = blockIdx.x % 50;
  const int i0 = it * 128 + w * 32;
  const int jb0 = jt * 128;
  constexpr int NKS = KD / 32;

  // A fragments resident in registers (2 m-tiles x K)
  bf16x8 afr[2][NKS];
#pragma unroll
  for (int mt = 0; mt < 2; ++mt)
#pragma unroll
    for (int ks = 0; ks < NKS; ++ks)
      afr[mt][ks] = *(const bf16x8*)(Lt + (size_t)(i0 + mt * 16 + jl) * KD + ks * 32 + q * 8);

  // Stage B tile [128 j][KD] with XOR-8 16B-chunk swizzle
  if constexpr (KD == 256) {
#pragma unroll
    for (int cc = 0; cc < 16; ++cc) {
      int jr = w * 32 + cc * 2 + (lane >> 5);
      int cp = lane & 31;
      int ch = (cp & ~7) | ((cp ^ jr) & 7);
      *(u32x4*)(Bs + jr * 256 + cp * 8) =
          *(const u32x4*)(Rt + (size_t)(jb0 + jr) * 256 + ch * 8);
    }
  } else {
#pragma unroll
    for (int cc = 0; cc < 8; ++cc) {
      int jr = w * 32 + cc * 4 + (lane >> 4);
      int cp = lane & 15;
      int ch = (cp & ~7) | ((cp ^ jr) & 7);
      *(u32x4*)(Bs + jr * 128 + cp * 8) =
          *(const u32x4*)(Rt + (size_t)(jb0 + jr) * 128 + ch * 8);
    }
  }
  __syncthreads();

  f32x4 s[2][8];
#pragma unroll
  for (int mt = 0; mt < 2; ++mt)
#pragma unroll
    for (int nf = 0; nf < 8; ++nf) s[mt][nf] = (f32x4){0.f, 0.f, 0.f, 0.f};

#pragma unroll
  for (int nf = 0; nf < 8; ++nf) {
    const int row = nf * 16 + jl;
#pragma unroll
    for (int ks = 0; ks < NKS; ++ks) {
      const int ch = (ks * 4 + q) ^ (jl & 7);    // un-swizzle
      bf16x8 b = *(const bf16x8*)(Bs + row * KD + ch * 8);
      s[0][nf] = MFMA(afr[0][ks], b, s[0][nf]);
      s[1][nf] = MFMA(afr[1][ks], b, s[1][nf]);
    }
  }
  __syncthreads();                               // Bs reads done -> reuse as T16

  u16* T16 = Bs + w * (16 * 136);                // per-wave 16x136 buffer
  const int it16b = i0 >> 4;                     // = it*8 + w*2
#pragma unroll
  for (int mt = 0; mt < 2; ++mt) {
    // exp + row sums
    float rs[4] = {0.f, 0.f, 0.f, 0.f};
#pragma unroll
    for (int nf = 0; nf < 8; ++nf)
#pragma unroll
      for (int r = 0; r < 4; ++r) {
        float p = __expf(s[mt][nf][r]);
        s[mt][nf][r] = p;
        rs[r] += p;
      }
#pragma unroll
    for (int d = 1; d < 16; d <<= 1)
#pragma unroll
      for (int r = 0; r < 4; ++r) rs[r] += __shfl_xor(rs[r], d);
    if (jl == 0) {
#pragma unroll
      for (int r = 0; r < 4; ++r)
        atomicAdd(&lv[i0 + mt * 16 + q * 4 + r], rs[r]);
    }
    // transpose C-frags -> per-wave LDS
#pragma unroll
    for (int nf = 0; nf < 8; ++nf)
#pragma unroll
      for (int r = 0; r < 4; ++r)
        T16[(q * 4 + r) * 136 + nf * 16 + jl] = f2b(s[mt][nf][r]);
    __syncthreads();                             // T16 writes -> vector reads
    // coalesced tiled stores: lane = row jl, 16 j's
#pragma unroll
    for (int jh = 0; jh < 2; ++jh) {
      const size_t tb = ((size_t)(jt * 2 + jh) * 400 + it16b + mt) * 1024;
      bf16x8 v0 = *(const bf16x8*)(T16 + jl * 136 + jh * 64 + q * 16);
      bf16x8 v1 = *(const bf16x8*)(T16 + jl * 136 + jh * 64 + q * 16 + 8);
      *(bf16x8*)(P + tb + jl * 64 + q * 16) = v0;
      *(bf16x8*)(P + tb + jl * 64 + q * 16 + 8) = v1;
    }
    __syncthreads();                             // reads done -> next mt writes
  }
}

// ---------------------------------------------------------------------------
// pv_k: O[i][c] += P . V^T.  Block = 128i x 128c, jp=10 (640 j), 5 steps
// of 128 j. A-frags DIRECT from tiled P (global); V staged in LDS (32KB).
// grid <<<500, 256>>>.
// ---------------------------------------------------------------------------
__global__ __launch_bounds__(256, 3) void pv_k(
    const u16* __restrict__ Pt,     // tiled P
    const u16* __restrict__ Vm,     // [128][HW]
    float* __restrict__ O)          // [HW][128]
{
  __shared__ __align__(16) u16 Vs[128 * 128];    // 32 KB
  const int t = threadIdx.x, w = t >> 6, lane = t & 63, jl = lane & 15, q = lane >> 4;
  const int it = blockIdx.x / 10, jp = blockIdx.x % 10;
  const int i0 = it * 128;
  const int it16 = it * 8 + w * 2;

  f32x4 o[2][8];
#pragma unroll
  for (int mt = 0; mt < 2; ++mt)
#pragma unroll
    for (int cf = 0; cf < 8; ++cf) o[mt][cf] = (f32x4){0.f, 0.f, 0.f, 0.f};

  for (int stp = 0; stp < 5; ++stp) {
    const int jj = jp * 640 + stp * 128;
    __syncthreads();
    // stage V tile [128 c][128 j], XOR-8 chunk swizzle, 8 chunks/thread
#pragma unroll
    for (int k = 0; k < 8; ++k) {
      int cidx = t + k * 256;
      int row = cidx >> 4, cp = cidx & 15;
      int ch = cp ^ (row & 7);
      *(u32x4*)(Vs + row * 128 + cp * 8) =
          *(const u32x4*)(Vm + (size_t)row * HW + jj + ch * 8);
    }
    __syncthreads();
#pragma unroll
    for (int ks2 = 0; ks2 < 4; ++ks2) {
      const size_t jt = (size_t)(jj >> 6) + (ks2 >> 1);
      const size_t pbase = (jt * 400 + it16) * 1024 + jl * 64 + (ks2 & 1) * 32 + q * 8;
      bf16x8 a0 = *(const bf16x8*)(Pt + pbase);
      bf16x8 a1 = *(const bf16x8*)(Pt + pbase + 1024);
      const int ch = ((ks2 * 4 + q) ^ (jl & 7)) * 8;
#pragma unroll
      for (int cf = 0; cf < 8; ++cf) {
        bf16x8 b = *(const bf16x8*)(Vs + (cf * 16 + jl) * 128 + ch);
        o[0][cf] = MFMA(a0, b, o[0][cf]);
        o[1][cf] = MFMA(a1, b, o[1][cf]);
      }
    }
  }
  // atomic accumulate into O (L2-resident, 3.3 MB)
#pragma unroll
  for (int mt = 0; mt < 2; ++mt) {
    const int ib = i0 + w * 32 + mt * 16 + q * 4;
#pragma unroll
    for (int cf = 0; cf < 8; ++cf) {
      const int c = cf * 16 + jl;
#pragma unroll
      for (int r = 0; r < 4; ++r)
        atomicAdd(&O[(size_t)(ib + r) * 128 + c], o[mt][cf][r]);
    }
  }
}

// ---------------------------------------------------------------------------
// final_k: out[d][i] = x[d][i] + silu(o1.w2b + b2e) + silu(o2.w3b + b3e),
// o?[i][c] = O[h][i][c] / l[h][i], built as bf16 A-frags on the fly.
// grid dim3(100, 2), 256 thr.
// ---------------------------------------------------------------------------
__global__ __launch_bounds__(256) void final_k(
    const float* __restrict__ Obuf,    // [2][HW][128]
    const float* __restrict__ lbuf,    // [2][HW]
    const u16* __restrict__ w2b, const float* __restrict__ b2e,
    const u16* __restrict__ w3b, const float* __restrict__ b3e,
    const float* __restrict__ x, float* __restrict__ outp)
{
  const int t = threadIdx.x, w = t >> 6, lane = t & 63, jl = lane & 15, q = lane >> 4;
  const int i0 = blockIdx.x * 64 + w * 16;
  const int nc = blockIdx.y;
  const int row = i0 + jl;

  const float inv1 = 1.0f / lbuf[row];
  const float inv2 = 1.0f / lbuf[HW + row];
  const float* O1 = Obuf + (size_t)row * 128;
  const float* O2 = Obuf + (size_t)(HW + row) * 128;

  f32x4 a1[8], a2[8];
#pragma unroll
  for (int nf = 0; nf < 8; ++nf) {
    a1[nf] = (f32x4){0.f, 0.f, 0.f, 0.f};
    a2[nf] = (f32x4){0.f, 0.f, 0.f, 0.f};
  }
#pragma unroll
  for (int ks = 0; ks < 4; ++ks) {
    f32x4 s1a = *(const f32x4*)(O1 + ks * 32 + q * 8);
    f32x4 s1b = *(const f32x4*)(O1 + ks * 32 + q * 8 + 4);
    f32x4 s2a = *(const f32x4*)(O2 + ks * 32 + q * 8);
    f32x4 s2b = *(const f32x4*)(O2 + ks * 32 + q * 8 + 4);
    bf16x8 fa1 = pack8(s1a, s1b, inv1);
    bf16x8 fa2 = pack8(s2a, s2b, inv2);
#pragma unroll
    for (int nf = 0; nf < 8; ++nf) {
      bf16x8 b2f = *(const bf16x8*)(w2b + (size_t)(nc * 128 + nf * 16 + jl) * 128 + ks * 32 + q * 8);
      bf16x8 b3f = *(const bf16x8*)(w3b + (size_t)(nc * 128 + nf * 16 + jl) * 128 + ks * 32 + q * 8);
      a1[nf] = MFMA(fa1, b2f, a1[nf]);
      a2[nf] = MFMA(fa2, b3f, a2[nf]);
    }
  }
#pragma unroll
  for (int nf = 0; nf < 8; ++nf) {
    const int d = nc * 128 + nf * 16 + jl;
    const float bb2 = b2e[d], bb3 = b3e[d];
    const size_t base = (size_t)d * HW + i0 + q * 4;
    f32x4 xv = *(const f32x4*)(x + base);
    f32x4 rv;
#pragma unroll
    for (int r = 0; r < 4; ++r)
      rv[r] = xv[r] + silu_f(a1[nf][r] + bb2) + silu_f(a2[nf][r] + bb3);
    *(f32x4*)(outp + base) = rv;
  }
}

// ---------------------------------------------------------------------------
extern "C" void kernel_launch(void* const* d_in, const int* in_sizes, int n_in,
                              void* d_out, int out_size, void* d_ws, size_t ws_size,
                              hipStream_t stream)
{
  (void)in_sizes; (void)n_in; (void)out_size; (void)ws_size;
  const float* x   = (const float*)d_in[0];
  const float* w1  = (const float*)d_in[1];
  const float* g1  = (const float*)d_in[2];
  const float* b1  = (const float*)d_in[3];
  const float* m1  = (const float*)d_in[4];
  const float* v1  = (const float*)d_in[5];
  const float* w2  = (const float*)d_in[6];
  const float* g2  = (const float*)d_in[7];
  const float* b2  = (const float*)d_in[8];
  const float* m2  = (const float*)d_in[9];
  const float* v2  = (const float*)d_in[10];
  const float* w3  = (const float*)d_in[11];
  const float* g3  = (const float*)d_in[12];
  const float* b3  = (const float*)d_in[13];
  const float* m3  = (const float*)d_in[14];
  const float* v3  = (const float*)d_in[15];
  const float* wq  = (const float*)d_in[16];
  const float* bq  = (const float*)d_in[17];
  const float* wk  = (const float*)d_in[18];
  const float* bk  = (const float*)d_in[19];
  const float* wv  = (const float*)d_in[20];
  const float* bv  = (const float*)d_in[21];
  const float* wp  = (const float*)d_in[22];
  const float* bp  = (const float*)d_in[23];
  const float* rel_h = (const float*)d_in[24];
  const float* rel_w = (const float*)d_in[25];
  const float* ef_h  = (const float*)d_in[26];
  const float* ef_w  = (const float*)d_in[27];
  float* outp = (float*)d_out;

  char* ws = (char*)d_ws;
  size_t off = 0;
  auto alloc = [&](size_t bytes) -> void* {
    void* p = ws + off;
    off += (bytes + 511) & ~(size_t)511;
    return p;
  };
  u16* LT    = (u16*)alloc((size_t)HW * 256 * 2);
  u16* RT    = (u16*)alloc((size_t)HW * 256 * 2);
  u16* pT    = (u16*)alloc((size_t)HW * 128 * 2);
  u16* efT   = (u16*)alloc((size_t)HW * 128 * 2);
  u16* efc   = (u16*)alloc((size_t)HW * 128 * 2);
  u16* Vv    = (u16*)alloc((size_t)HW * 128 * 2);
  u16* Pbuf  = (u16*)alloc((size_t)HW * HW * 2);            // 81.9 MB (tiled)
  float* Obuf = (float*)alloc((size_t)2 * HW * 128 * 4);    // 6.55 MB
  float* lbuf = (float*)alloc((size_t)2 * HW * 4);
  u16* w1b   = (u16*)alloc(128 * 256 * 2);
  float* b1e = (float*)alloc(128 * 4);
  u16* Wcat  = (u16*)alloc(512 * 128 * 2);
  float* bcat = (float*)alloc(512 * 4);
  u16* w2b   = (u16*)alloc(256 * 128 * 2);
  float* b2e = (float*)alloc(256 * 4);
  u16* w3b   = (u16*)alloc(256 * 128 * 2);
  float* b3e = (float*)alloc(256 * 4);

  prep_all<<<176, 256, 0, stream>>>(rel_h, rel_w, ef_h, ef_w,
                                    w1, g1, b1, m1, v1, w2, g2, b2, m2, v2,
                                    w3, g3, b3, m3, v3, wq, bq, wk, bk, wv, bv, wp, bp,
                                    LT, efT, efc,
                                    w1b, b1e, Wcat, bcat, w2b, b2e, w3b, b3e,
                                    Obuf, lbuf);
  front_k<<<200, 128, 0, stream>>>(x, w1b, b1e, Wcat, bcat, LT, RT, Vv, pT);
  // head 1
  score_k<256, 2><<<2500, 256, 0, stream>>>(LT, RT, Pbuf, lbuf);
  pv_k<<<500, 256, 0, stream>>>(Pbuf, Vv, Obuf);
  // head 2 (reuses Pbuf)
  score_k<128, 3><<<2500, 256, 0, stream>>>(pT, efT, Pbuf, lbuf + HW);
  pv_k<<<500, 256, 0, stream>>>(Pbuf, efc, Obuf + (size_t)HW * 128);
  final_k<<<dim3(100, 2), 256, 0, stream>>>(Obuf, lbuf, w2b, b2e, w3b, b3e, x, outp);
}